// Round 5
// baseline (301.714 us; speedup 1.0000x reference)
//
#include <hip/hip_runtime.h>

// KernelizedHeadAttention, B=4 S=1024 D=2048 H=16 DH=128 DHID=128 DKER=64
// out[s] = [ sum_t (m? score+eps : exp(saw)) * v[t] ] / (rowsum_s + eps + exp(lse_s))
// R5: occupancy + conflict + DRAM-granularity fixes on the R4 2-phase pipeline:
//   - p merged into ebuf (in-place merge) -> LDS 51.2KB -> 3 blocks/CU
//   - ebuf [64][72] stride: staging write ~4-way, merge reads 2-way (free)
//   - saw loads 256B/row granularity (16 lanes/row), prefetch distance 2 (A/B reg sets)

typedef __bf16 bf16_t;
typedef __attribute__((ext_vector_type(8))) __bf16 bf16x8;
typedef __attribute__((ext_vector_type(4))) float f32x4;

#define MFMA(a, b, c) __builtin_amdgcn_mfma_f32_16x16x32_bf16((a), (b), (c), 0, 0, 0)

typedef __attribute__((address_space(3))) void as3_void;
typedef __attribute__((address_space(1))) const void as1_void;
static __device__ __forceinline__ void gload16(const void* g, void* l) {
    __builtin_amdgcn_global_load_lds((as1_void*)g, (as3_void*)l, 16, 0, 0);
}

static __device__ __forceinline__ float gelu_exact(float x) {
    return 0.5f * x * (1.0f + erff(x * 0.70710678118654752f));
}

// ---------------- weights: convert f32 -> bf16, transposed for B-fragments ----------------
__global__ __launch_bounds__(256) void conv_weights_kernel(
    const float* __restrict__ wq1, const float* __restrict__ wk1,
    const float* __restrict__ wq2, const float* __restrict__ wk2,
    const float* __restrict__ iK,
    bf16_t* __restrict__ wq1t, bf16_t* __restrict__ wk1t,
    bf16_t* __restrict__ wq2t, bf16_t* __restrict__ wk2t,
    bf16_t* __restrict__ iKt)
{
    const int idx = blockIdx.x * 256 + threadIdx.x;
    if (idx < 16 * 128 * 128) {           // [h][e][d] <- [h][d][e]
        int h = idx >> 14, e = (idx >> 7) & 127, d = idx & 127;
        wq1t[idx] = (bf16_t)wq1[(h << 14) + (d << 7) + e];
        wk1t[idx] = (bf16_t)wk1[(h << 14) + (d << 7) + e];
    }
    if (idx < 16 * 64 * 128) {            // [h][f][e] <- [h][e][f]
        int h = idx >> 13, f = (idx >> 7) & 63, e = idx & 127;
        wq2t[idx] = (bf16_t)wq2[(h << 13) + (e << 6) + f];
        wk2t[idx] = (bf16_t)wk2[(h << 13) + (e << 6) + f];
    }
    if (idx < 16 * 64 * 64) {             // [h][g][f] <- [h][f][g]
        int h = idx >> 12, g = (idx >> 6) & 63, f = idx & 63;
        iKt[idx] = (bf16_t)iK[(h << 12) + (f << 6) + g];
    }
}

// ---------------- V: [B,S,H,128] f32 -> vT tiled [B,H,tt(16),128,64] bf16 ---------------
__global__ __launch_bounds__(256) void conv_v_kernel(
    const float* __restrict__ v, bf16_t* __restrict__ vT)
{
    __shared__ bf16_t tr[128][72];
    const int bh = blockIdx.x, b = bh >> 4, h = bh & 15;
    const int tt = blockIdx.y;
    const int t0 = tt * 64;
    const int tid = threadIdx.x;
#pragma unroll
    for (int i = 0; i < 8; ++i) {
        int f4 = tid + 256 * i;                 // 2048 float4 = 64 t x 128 d
        int t = f4 >> 5, c4 = f4 & 31;
        const float4 vv = *reinterpret_cast<const float4*>(
            &v[((size_t)b * 1024 + t0 + t) * 2048 + h * 128 + c4 * 4]);
        tr[c4 * 4 + 0][t] = (bf16_t)vv.x;
        tr[c4 * 4 + 1][t] = (bf16_t)vv.y;
        tr[c4 * 4 + 2][t] = (bf16_t)vv.z;
        tr[c4 * 4 + 3][t] = (bf16_t)vv.w;
    }
    __syncthreads();
#pragma unroll
    for (int i = 0; i < 32; ++i) {
        int e = tid + 256 * i;                  // 8192 bf16
        int d = e >> 6, tl = e & 63;
        vT[(((size_t)bh * 16 + tt) * 128 + d) * 64 + tl] = tr[d][tl];
    }
}

// ---------------- feature maps: qf = |gelu(gelu(q W1) W2)|, kf path w/ interaction ------
__global__ __launch_bounds__(256) void feat_kernel(
    const float* __restrict__ q, const float* __restrict__ k,
    const bf16_t* __restrict__ wq1t, const bf16_t* __restrict__ wq2t,
    const bf16_t* __restrict__ wk1t, const bf16_t* __restrict__ wk2t,
    const bf16_t* __restrict__ iKt,
    const float* __restrict__ sD, const float* __restrict__ sD2,
    bf16_t* __restrict__ qf, bf16_t* __restrict__ kf)
{
    __shared__ bf16_t xa[64][136];
    __shared__ bf16_t h1[64][136];
    __shared__ bf16_t k2[64][72];

    const int tid = threadIdx.x;
    const int lane = tid & 63, w = tid >> 6;
    const int lr = lane & 15, lg = lane >> 4;
    const int row0 = blockIdx.x * 64;
    const int h = blockIdx.y;
    const int path = blockIdx.z;               // 0 = q, 1 = k

    const float* X = path ? k : q;
    const bf16_t* w1t = path ? wk1t : wq1t;
    const bf16_t* w2t = path ? wk2t : wq2t;
    bf16_t* outp = path ? kf : qf;

#pragma unroll
    for (int i = 0; i < 8; ++i) {
        int f4 = tid + 256 * i;
        int r = f4 >> 5, c4 = f4 & 31;
        const float4 vv = *reinterpret_cast<const float4*>(
            &X[(size_t)(row0 + r) * 2048 + h * 128 + c4 * 4]);
        xa[r][c4 * 4 + 0] = (bf16_t)vv.x;
        xa[r][c4 * 4 + 1] = (bf16_t)vv.y;
        xa[r][c4 * 4 + 2] = (bf16_t)vv.z;
        xa[r][c4 * 4 + 3] = (bf16_t)vv.w;
    }
    __syncthreads();

    bf16x8 a1[4];
#pragma unroll
    for (int kk = 0; kk < 4; ++kk)
        a1[kk] = *reinterpret_cast<const bf16x8*>(&xa[w * 16 + lr][kk * 32 + lg * 8]);
#pragma unroll
    for (int nt = 0; nt < 8; ++nt) {
        f32x4 acc = {0.f, 0.f, 0.f, 0.f};
#pragma unroll
        for (int kk = 0; kk < 4; ++kk) {
            bf16x8 bfr = *reinterpret_cast<const bf16x8*>(
                &w1t[(size_t)h * 16384 + (nt * 16 + lr) * 128 + kk * 32 + lg * 8]);
            acc = MFMA(a1[kk], bfr, acc);
        }
#pragma unroll
        for (int r = 0; r < 4; ++r)
            h1[w * 16 + lg * 4 + r][nt * 16 + lr] = (bf16_t)gelu_exact(acc[r]);
    }
    __syncthreads();

    bf16x8 a2[4];
#pragma unroll
    for (int kk = 0; kk < 4; ++kk)
        a2[kk] = *reinterpret_cast<const bf16x8*>(&h1[w * 16 + lr][kk * 32 + lg * 8]);

    if (path == 0) {
#pragma unroll
        for (int nt = 0; nt < 4; ++nt) {
            f32x4 acc = {0.f, 0.f, 0.f, 0.f};
#pragma unroll
            for (int kk = 0; kk < 4; ++kk) {
                bf16x8 bfr = *reinterpret_cast<const bf16x8*>(
                    &w2t[(size_t)h * 8192 + (nt * 16 + lr) * 128 + kk * 32 + lg * 8]);
                acc = MFMA(a2[kk], bfr, acc);
            }
#pragma unroll
            for (int r = 0; r < 4; ++r) {
                int n = row0 + w * 16 + lg * 4 + r;
                int bb = n >> 10, s = n & 1023;
                outp[(((size_t)bb * 16 + h) * 1024 + s) * 64 + nt * 16 + lr] =
                    (bf16_t)fabsf(gelu_exact(acc[r]));
            }
        }
    } else {
#pragma unroll
        for (int nt = 0; nt < 4; ++nt) {
            f32x4 acc = {0.f, 0.f, 0.f, 0.f};
#pragma unroll
            for (int kk = 0; kk < 4; ++kk) {
                bf16x8 bfr = *reinterpret_cast<const bf16x8*>(
                    &w2t[(size_t)h * 8192 + (nt * 16 + lr) * 128 + kk * 32 + lg * 8]);
                acc = MFMA(a2[kk], bfr, acc);
            }
#pragma unroll
            for (int r = 0; r < 4; ++r) {
                int f = nt * 16 + lr;
                k2[w * 16 + lg * 4 + r][f] =
                    (bf16_t)(fabsf(sD[h * 64 + f]) * gelu_exact(acc[r]));
            }
        }
        __syncthreads();
        bf16x8 a3[2];
#pragma unroll
        for (int kk = 0; kk < 2; ++kk)
            a3[kk] = *reinterpret_cast<const bf16x8*>(&k2[w * 16 + lr][kk * 32 + lg * 8]);
#pragma unroll
        for (int nt = 0; nt < 4; ++nt) {
            f32x4 acc = {0.f, 0.f, 0.f, 0.f};
#pragma unroll
            for (int kk = 0; kk < 2; ++kk) {
                bf16x8 bfr = *reinterpret_cast<const bf16x8*>(
                    &iKt[(size_t)h * 4096 + (nt * 16 + lr) * 64 + kk * 32 + lg * 8]);
                acc = MFMA(a3[kk], bfr, acc);
            }
#pragma unroll
            for (int r = 0; r < 4; ++r) {
                int row = w * 16 + lg * 4 + r;
                int g = nt * 16 + lr;
                float base = (float)k2[row][g];
                float kv = fabsf(base + acc[r] * sD2[h * 64 + g]);
                int n = row0 + row;
                int bb = n >> 10, s = n & 1023;
                outp[(((size_t)bb * 16 + h) * 1024 + s) * 64 + g] = (bf16_t)kv;
            }
        }
    }
}

// ---------------- fused attention: 2-phase async pipeline, merged ebuf ------------------
__global__ __launch_bounds__(256, 3) void attn_fused_kernel(
    const bf16_t* __restrict__ qf, const bf16_t* __restrict__ kf,
    const bf16_t* __restrict__ vT,
    const unsigned char* __restrict__ mask8,
    const float* __restrict__ saw, const float* __restrict__ lse,
    float* __restrict__ out)
{
    __shared__ bf16_t vbuf[2][128 * 64];    // XOR-swizzled V tiles (16KB each)
    __shared__ bf16_t ebuf[2][64 * 72];     // exp/mask tile, merged in place (9.2KB each)
    __shared__ int mflag;

    const int tid = threadIdx.x;
    const int lane = tid & 63, w = tid >> 6;
    const int lr = lane & 15, lg = lane >> 4;

    // XCD swizzle: all 16 s-blocks of a bh share one XCD's L2
    const int di = blockIdx.y * 16 + blockIdx.x;   // 0..1023
    const int xcd = di & 7, rr = di >> 3;
    const int bh = xcd + 8 * (rr >> 4);
    const int s0 = (rr & 15) * 64;
    const int b = bh >> 4, h = bh & 15;

    if (tid == 0) {   // detect mask storage width: int32 => bytes 4i+1 all zero
        unsigned a = 0;
        for (int i = 0; i < 64; ++i) a |= mask8[4 * i + 1];
        mflag = (a == 0) ? 1 : 0;
    }
    __syncthreads();
    const bool mask_is_int = (mflag != 0);
    const int* mask32 = (const int*)mask8;

    // staging mapping: pass j: row = (tid>>4) + 16*j, cols (tid&15)*4 .. +3
    // -> per wave-instr: 4 rows x 256B contiguous (max granularity for 64-col tile)
    const int strow = tid >> 4;                    // 0..15
    const int stcol = (tid & 15) * 4;              // 0..60
    const size_t saw_base = ((size_t)bh << 20) + (size_t)(s0 + strow) * 1024 + stcol;
    const size_t m_base   = ((size_t)b << 20) + (size_t)(s0 + strow) * 1024 + stcol;

    // vT staging mapping (inverse-swizzled global source, linear LDS dest)
    const int vrow = tid >> 3;                     // 0..31 (+32 per j-round)
    const int vcol8 = (tid & 7) ^ (vrow & 7);
    const bf16_t* vt_bh = vT + (size_t)bh * 131072;

    bf16x8 aq0, aq1;
    {
        const size_t qb = ((size_t)bh * 1024 + s0 + w * 16 + lr) * 64;
        aq0 = *reinterpret_cast<const bf16x8*>(&qf[qb + lg * 8]);
        aq1 = *reinterpret_cast<const bf16x8*>(&qf[qb + 32 + lg * 8]);
    }

    const f32x4 fzero = {0.f, 0.f, 0.f, 0.f};
    f32x4 oacc[8];
#pragma unroll
    for (int i = 0; i < 8; ++i) oacc[i] = fzero;
    float rowsum[4] = {0.f, 0.f, 0.f, 0.f};

#define STAGE_VT(BUF, TILE)                                                      \
    {                                                                            \
        const bf16_t* vg = vt_bh + (size_t)(TILE) * 8192 + vcol8 * 8;            \
        char* lb = (char*)&vbuf[BUF][0] + w * 1024;                              \
        _Pragma("unroll")                                                        \
        for (int j = 0; j < 4; ++j)                                              \
            gload16(vg + (size_t)(32 * j + vrow) * 64, lb + j * 4096);           \
    }

#define LOAD_SAWM(TILE, SS, MI, MU)                                              \
    {                                                                            \
        _Pragma("unroll")                                                        \
        for (int j = 0; j < 4; ++j)                                              \
            SS[j] = *reinterpret_cast<const float4*>(                            \
                &saw[saw_base + (size_t)(TILE) * 64 + (size_t)j * 16384]);       \
        if (mask_is_int) {                                                       \
            _Pragma("unroll")                                                    \
            for (int j = 0; j < 4; ++j)                                          \
                MI[j] = *reinterpret_cast<const int4*>(                          \
                    &mask32[m_base + (size_t)(TILE) * 64 + (size_t)j * 16384]);  \
        } else {                                                                 \
            _Pragma("unroll")                                                    \
            for (int j = 0; j < 4; ++j)                                          \
                MU[j] = *reinterpret_cast<const unsigned*>(                      \
                    &mask8[m_base + (size_t)(TILE) * 64 + (size_t)j * 16384]);   \
        }                                                                        \
    }

#define WRITE_EBUF(BUF, SS, MI, MU)                                              \
    {                                                                            \
        _Pragma("unroll")                                                        \
        for (int j = 0; j < 4; ++j) {                                            \
            int m0, m1, m2, m3;                                                  \
            if (mask_is_int) {                                                   \
                m0 = MI[j].x; m1 = MI[j].y; m2 = MI[j].z; m3 = MI[j].w;          \
            } else {                                                             \
                m0 = (int)(MU[j] & 255u);        m1 = (int)((MU[j] >> 8) & 255u);\
                m2 = (int)((MU[j] >> 16) & 255u); m3 = (int)(MU[j] >> 24);       \
            }                                                                    \
            bf16_t e[4];                                                         \
            e[0] = m0 ? (bf16_t)(-1.0f) : (bf16_t)__expf(SS[j].x);               \
            e[1] = m1 ? (bf16_t)(-1.0f) : (bf16_t)__expf(SS[j].y);               \
            e[2] = m2 ? (bf16_t)(-1.0f) : (bf16_t)__expf(SS[j].z);               \
            e[3] = m3 ? (bf16_t)(-1.0f) : (bf16_t)__expf(SS[j].w);               \
            *reinterpret_cast<uint2*>(&ebuf[BUF][(strow + 16 * j) * 72 + stcol]) \
                = *reinterpret_cast<const uint2*>(e);                            \
        }                                                                        \
    }

// one t-tile phase: QK^T -> in-place merge in ebuf[CUR] -> PV from vbuf[CUR]
#define PHASE(CUR, T0)                                                           \
    {                                                                            \
        f32x4 c[4];                                                              \
        _Pragma("unroll")                                                        \
        for (int nt = 0; nt < 4; ++nt) {                                         \
            f32x4 acc = fzero;                                                   \
            const size_t kb = ((size_t)bh * 1024 + (T0) + nt * 16 + lr) * 64;    \
            bf16x8 kb0 = *reinterpret_cast<const bf16x8*>(&kf[kb + lg * 8]);     \
            bf16x8 kb1 = *reinterpret_cast<const bf16x8*>(&kf[kb + 32 + lg * 8]);\
            acc = MFMA(aq0, kb0, acc);                                           \
            acc = MFMA(aq1, kb1, acc);                                           \
            c[nt] = acc;                                                         \
        }                                                                        \
        _Pragma("unroll")                                                        \
        for (int nt = 0; nt < 4; ++nt) {                                         \
            _Pragma("unroll")                                                    \
            for (int r = 0; r < 4; ++r) {                                        \
                const int eoff = (w * 16 + lg * 4 + r) * 72 + nt * 16 + lr;      \
                float pe = (float)ebuf[CUR][eoff];                               \
                float sc = c[nt][r];                                             \
                bool msk = pe < 0.f;                                             \
                float wv = msk ? (sc + 1e-6f) : pe;                              \
                rowsum[r] += msk ? sc : 0.f;                                     \
                ebuf[CUR][eoff] = (bf16_t)wv;                                    \
            }                                                                    \
        }                                                                        \
        asm volatile("s_waitcnt lgkmcnt(0)" ::: "memory");                       \
        __builtin_amdgcn_sched_barrier(0);                                       \
        bf16x8 ap0 = *reinterpret_cast<const bf16x8*>(                           \
            &ebuf[CUR][(w * 16 + lr) * 72 + lg * 8]);                            \
        bf16x8 ap1 = *reinterpret_cast<const bf16x8*>(                           \
            &ebuf[CUR][(w * 16 + lr) * 72 + 32 + lg * 8]);                       \
        const char* vb = (const char*)&vbuf[CUR][0];                             \
        _Pragma("unroll")                                                        \
        for (int dt = 0; dt < 8; ++dt) {                                         \
            const int row = dt * 16 + lr;                                        \
            bf16x8 v0 = *reinterpret_cast<const bf16x8*>(                        \
                vb + row * 128 + ((lg * 16) ^ xorv));                            \
            bf16x8 v1 = *reinterpret_cast<const bf16x8*>(                        \
                vb + row * 128 + ((64 + lg * 16) ^ xorv));                       \
            oacc[dt] = MFMA(ap0, v0, oacc[dt]);                                  \
            oacc[dt] = MFMA(ap1, v1, oacc[dt]);                                  \
        }                                                                        \
    }

    float4 sawA[4], sawB[4];
    int4 miA[4], miB[4];
    unsigned muA[4], muB[4];
    const int xorv = (lr & 7) << 4;

    // ---- prologue: ebuf[0] <- tile0; sawA <- tile1; vbuf[0] <- tile0
    LOAD_SAWM(0, sawA, miA, muA);
    WRITE_EBUF(0, sawA, miA, muA);
    LOAD_SAWM(1, sawA, miA, muA);
    STAGE_VT(0, 0);
    __syncthreads();

    for (int i = 0; i < 16; i += 2) {
        // phase A: tile i (cur=0)
        STAGE_VT(1, i + 1);
        LOAD_SAWM((i + 2) & 15, sawB, miB, muB);
        PHASE(0, i * 64);
        WRITE_EBUF(1, sawA, miA, muA);          // tile i+1
        __syncthreads();
        // phase B: tile i+1 (cur=1)
        STAGE_VT(0, (i + 2) & 15);
        LOAD_SAWM((i + 3) & 15, sawA, miA, muA);
        PHASE(1, (i + 1) * 64);
        WRITE_EBUF(0, sawB, miB, muB);          // tile i+2
        __syncthreads();
    }

    // rowsum reduce across the 16 lr lanes
#pragma unroll
    for (int r = 0; r < 4; ++r) {
        float s = rowsum[r];
#pragma unroll
        for (int m = 1; m < 16; m <<= 1) s += __shfl_xor(s, m);
        rowsum[r] = s;
    }
    float invden[4];
#pragma unroll
    for (int r = 0; r < 4; ++r) {
        const int srow = s0 + w * 16 + lg * 4 + r;
        invden[r] = 1.0f / (rowsum[r] + 1e-6f + __expf(lse[(size_t)bh * 1024 + srow]));
    }
#pragma unroll
    for (int dt = 0; dt < 8; ++dt) {
#pragma unroll
        for (int r = 0; r < 4; ++r) {
            const int srow = s0 + w * 16 + lg * 4 + r;
            out[((size_t)b * 1024 + srow) * 2048 + h * 128 + dt * 16 + lr] =
                oacc[dt][r] * invden[r];
        }
    }
#undef STAGE_VT
#undef LOAD_SAWM
#undef WRITE_EBUF
#undef PHASE
}

extern "C" void kernel_launch(void* const* d_in, const int* in_sizes, int n_in,
                              void* d_out, int out_size, void* d_ws, size_t ws_size,
                              hipStream_t stream)
{
    const float* q   = (const float*)d_in[0];
    const float* k   = (const float*)d_in[1];
    const float* v   = (const float*)d_in[2];
    const unsigned char* mask = (const unsigned char*)d_in[3];
    const float* lse = (const float*)d_in[4];
    const float* saw = (const float*)d_in[5];
    const float* wq1 = (const float*)d_in[6];
    const float* wk1 = (const float*)d_in[7];
    const float* wq2 = (const float*)d_in[8];
    const float* wk2 = (const float*)d_in[9];
    const float* iK  = (const float*)d_in[10];
    const float* sD  = (const float*)d_in[11];
    const float* sD2 = (const float*)d_in[12];
    float* out = (float*)d_out;

    bf16_t* wsb  = (bf16_t*)d_ws;
    bf16_t* wq1t = wsb;                    // 16*128*128 = 262144
    bf16_t* wk1t = wq1t + 262144;
    bf16_t* wq2t = wk1t + 262144;          // 16*64*128 = 131072
    bf16_t* wk2t = wq2t + 131072;
    bf16_t* iKt  = wk2t + 131072;          // 16*64*64  = 65536
    bf16_t* qf   = iKt  + 65536;           // 4*16*1024*64 = 4194304
    bf16_t* kf   = qf   + 4194304;
    bf16_t* vT   = kf   + 4194304;         // 4*16*128*1024 = 8388608 (tiled)
    // total ws use: ~35.3 MB

    conv_weights_kernel<<<dim3(1024), dim3(256), 0, stream>>>(
        wq1, wk1, wq2, wk2, iK, wq1t, wk1t, wq2t, wk2t, iKt);
    conv_v_kernel<<<dim3(64, 16), dim3(256), 0, stream>>>(v, vT);
    feat_kernel<<<dim3(64, 16, 2), dim3(256), 0, stream>>>(
        q, k, wq1t, wq2t, wk1t, wk2t, iKt, sD, sD2, qf, kf);
    attn_fused_kernel<<<dim3(16, 64), dim3(256), 0, stream>>>(
        qf, kf, vT, mask, saw, lse, out);
}

// Round 6
// 212.132 us; speedup vs baseline: 1.4223x; 1.4223x over previous
//
#include <hip/hip_runtime.h>

// KernelizedHeadAttention, B=4 S=1024 D=2048 H=16 DH=128 DHID=128 DKER=64
// out[s] = [ sum_t (m? score+eps : exp(saw)) * v[t] ] / (rowsum_s + eps + exp(lse_s))
// R6: eliminate the mid-phase vmcnt drain. R4/R5 consumed kf global loads at the top
// of the same phase they were issued -> s_waitcnt vmcnt(~0) drained the whole prefetch
// queue each phase. Now kf is register-prefetched one tile ahead (kfA/kfB), so every
// phase consumes ONLY data issued >= 1 phase earlier: counted vmcnt waits, single
// barrier drain covered by a full phase of compute. In-place ebuf merge (R5-verified),
// LDS 50.2KB, VGPR ~200 -> 2 blocks/CU -> clean 512x2 round balance on 1024 blocks.

typedef __bf16 bf16_t;
typedef __attribute__((ext_vector_type(8))) __bf16 bf16x8;
typedef __attribute__((ext_vector_type(4))) float f32x4;

#define MFMA(a, b, c) __builtin_amdgcn_mfma_f32_16x16x32_bf16((a), (b), (c), 0, 0, 0)

typedef __attribute__((address_space(3))) void as3_void;
typedef __attribute__((address_space(1))) const void as1_void;
static __device__ __forceinline__ void gload16(const void* g, void* l) {
    __builtin_amdgcn_global_load_lds((as1_void*)g, (as3_void*)l, 16, 0, 0);
}

static __device__ __forceinline__ float gelu_exact(float x) {
    return 0.5f * x * (1.0f + erff(x * 0.70710678118654752f));
}

// ---------------- weights: convert f32 -> bf16, transposed for B-fragments ----------------
__global__ __launch_bounds__(256) void conv_weights_kernel(
    const float* __restrict__ wq1, const float* __restrict__ wk1,
    const float* __restrict__ wq2, const float* __restrict__ wk2,
    const float* __restrict__ iK,
    bf16_t* __restrict__ wq1t, bf16_t* __restrict__ wk1t,
    bf16_t* __restrict__ wq2t, bf16_t* __restrict__ wk2t,
    bf16_t* __restrict__ iKt)
{
    const int idx = blockIdx.x * 256 + threadIdx.x;
    if (idx < 16 * 128 * 128) {           // [h][e][d] <- [h][d][e]
        int h = idx >> 14, e = (idx >> 7) & 127, d = idx & 127;
        wq1t[idx] = (bf16_t)wq1[(h << 14) + (d << 7) + e];
        wk1t[idx] = (bf16_t)wk1[(h << 14) + (d << 7) + e];
    }
    if (idx < 16 * 64 * 128) {            // [h][f][e] <- [h][e][f]
        int h = idx >> 13, f = (idx >> 7) & 63, e = idx & 127;
        wq2t[idx] = (bf16_t)wq2[(h << 13) + (e << 6) + f];
        wk2t[idx] = (bf16_t)wk2[(h << 13) + (e << 6) + f];
    }
    if (idx < 16 * 64 * 64) {             // [h][g][f] <- [h][f][g]
        int h = idx >> 12, g = (idx >> 6) & 63, f = idx & 63;
        iKt[idx] = (bf16_t)iK[(h << 12) + (f << 6) + g];
    }
}

// ---------------- V: [B,S,H,128] f32 -> vT tiled [B,H,tt(16),128,64] bf16 ---------------
__global__ __launch_bounds__(256) void conv_v_kernel(
    const float* __restrict__ v, bf16_t* __restrict__ vT)
{
    __shared__ bf16_t tr[128][72];
    const int bh = blockIdx.x, b = bh >> 4, h = bh & 15;
    const int tt = blockIdx.y;
    const int t0 = tt * 64;
    const int tid = threadIdx.x;
#pragma unroll
    for (int i = 0; i < 8; ++i) {
        int f4 = tid + 256 * i;                 // 2048 float4 = 64 t x 128 d
        int t = f4 >> 5, c4 = f4 & 31;
        const float4 vv = *reinterpret_cast<const float4*>(
            &v[((size_t)b * 1024 + t0 + t) * 2048 + h * 128 + c4 * 4]);
        tr[c4 * 4 + 0][t] = (bf16_t)vv.x;
        tr[c4 * 4 + 1][t] = (bf16_t)vv.y;
        tr[c4 * 4 + 2][t] = (bf16_t)vv.z;
        tr[c4 * 4 + 3][t] = (bf16_t)vv.w;
    }
    __syncthreads();
#pragma unroll
    for (int i = 0; i < 32; ++i) {
        int e = tid + 256 * i;                  // 8192 bf16
        int d = e >> 6, tl = e & 63;
        vT[(((size_t)bh * 16 + tt) * 128 + d) * 64 + tl] = tr[d][tl];
    }
}

// ---------------- feature maps: qf = |gelu(gelu(q W1) W2)|, kf path w/ interaction ------
__global__ __launch_bounds__(256) void feat_kernel(
    const float* __restrict__ q, const float* __restrict__ k,
    const bf16_t* __restrict__ wq1t, const bf16_t* __restrict__ wq2t,
    const bf16_t* __restrict__ wk1t, const bf16_t* __restrict__ wk2t,
    const bf16_t* __restrict__ iKt,
    const float* __restrict__ sD, const float* __restrict__ sD2,
    bf16_t* __restrict__ qf, bf16_t* __restrict__ kf)
{
    __shared__ bf16_t xa[64][136];
    __shared__ bf16_t h1[64][136];
    __shared__ bf16_t k2[64][72];

    const int tid = threadIdx.x;
    const int lane = tid & 63, w = tid >> 6;
    const int lr = lane & 15, lg = lane >> 4;
    const int row0 = blockIdx.x * 64;
    const int h = blockIdx.y;
    const int path = blockIdx.z;               // 0 = q, 1 = k

    const float* X = path ? k : q;
    const bf16_t* w1t = path ? wk1t : wq1t;
    const bf16_t* w2t = path ? wk2t : wq2t;
    bf16_t* outp = path ? kf : qf;

#pragma unroll
    for (int i = 0; i < 8; ++i) {
        int f4 = tid + 256 * i;
        int r = f4 >> 5, c4 = f4 & 31;
        const float4 vv = *reinterpret_cast<const float4*>(
            &X[(size_t)(row0 + r) * 2048 + h * 128 + c4 * 4]);
        xa[r][c4 * 4 + 0] = (bf16_t)vv.x;
        xa[r][c4 * 4 + 1] = (bf16_t)vv.y;
        xa[r][c4 * 4 + 2] = (bf16_t)vv.z;
        xa[r][c4 * 4 + 3] = (bf16_t)vv.w;
    }
    __syncthreads();

    bf16x8 a1[4];
#pragma unroll
    for (int kk = 0; kk < 4; ++kk)
        a1[kk] = *reinterpret_cast<const bf16x8*>(&xa[w * 16 + lr][kk * 32 + lg * 8]);
#pragma unroll
    for (int nt = 0; nt < 8; ++nt) {
        f32x4 acc = {0.f, 0.f, 0.f, 0.f};
#pragma unroll
        for (int kk = 0; kk < 4; ++kk) {
            bf16x8 bfr = *reinterpret_cast<const bf16x8*>(
                &w1t[(size_t)h * 16384 + (nt * 16 + lr) * 128 + kk * 32 + lg * 8]);
            acc = MFMA(a1[kk], bfr, acc);
        }
#pragma unroll
        for (int r = 0; r < 4; ++r)
            h1[w * 16 + lg * 4 + r][nt * 16 + lr] = (bf16_t)gelu_exact(acc[r]);
    }
    __syncthreads();

    bf16x8 a2[4];
#pragma unroll
    for (int kk = 0; kk < 4; ++kk)
        a2[kk] = *reinterpret_cast<const bf16x8*>(&h1[w * 16 + lr][kk * 32 + lg * 8]);

    if (path == 0) {
#pragma unroll
        for (int nt = 0; nt < 4; ++nt) {
            f32x4 acc = {0.f, 0.f, 0.f, 0.f};
#pragma unroll
            for (int kk = 0; kk < 4; ++kk) {
                bf16x8 bfr = *reinterpret_cast<const bf16x8*>(
                    &w2t[(size_t)h * 8192 + (nt * 16 + lr) * 128 + kk * 32 + lg * 8]);
                acc = MFMA(a2[kk], bfr, acc);
            }
#pragma unroll
            for (int r = 0; r < 4; ++r) {
                int n = row0 + w * 16 + lg * 4 + r;
                int bb = n >> 10, s = n & 1023;
                outp[(((size_t)bb * 16 + h) * 1024 + s) * 64 + nt * 16 + lr] =
                    (bf16_t)fabsf(gelu_exact(acc[r]));
            }
        }
    } else {
#pragma unroll
        for (int nt = 0; nt < 4; ++nt) {
            f32x4 acc = {0.f, 0.f, 0.f, 0.f};
#pragma unroll
            for (int kk = 0; kk < 4; ++kk) {
                bf16x8 bfr = *reinterpret_cast<const bf16x8*>(
                    &w2t[(size_t)h * 8192 + (nt * 16 + lr) * 128 + kk * 32 + lg * 8]);
                acc = MFMA(a2[kk], bfr, acc);
            }
#pragma unroll
            for (int r = 0; r < 4; ++r) {
                int f = nt * 16 + lr;
                k2[w * 16 + lg * 4 + r][f] =
                    (bf16_t)(fabsf(sD[h * 64 + f]) * gelu_exact(acc[r]));
            }
        }
        __syncthreads();
        bf16x8 a3[2];
#pragma unroll
        for (int kk = 0; kk < 2; ++kk)
            a3[kk] = *reinterpret_cast<const bf16x8*>(&k2[w * 16 + lr][kk * 32 + lg * 8]);
#pragma unroll
        for (int nt = 0; nt < 4; ++nt) {
            f32x4 acc = {0.f, 0.f, 0.f, 0.f};
#pragma unroll
            for (int kk = 0; kk < 2; ++kk) {
                bf16x8 bfr = *reinterpret_cast<const bf16x8*>(
                    &iKt[(size_t)h * 4096 + (nt * 16 + lr) * 64 + kk * 32 + lg * 8]);
                acc = MFMA(a3[kk], bfr, acc);
            }
#pragma unroll
            for (int r = 0; r < 4; ++r) {
                int row = w * 16 + lg * 4 + r;
                int g = nt * 16 + lr;
                float base = (float)k2[row][g];
                float kv = fabsf(base + acc[r] * sD2[h * 64 + g]);
                int n = row0 + row;
                int bb = n >> 10, s = n & 1023;
                outp[(((size_t)bb * 16 + h) * 1024 + s) * 64 + g] = (bf16_t)kv;
            }
        }
    }
}

// ---------------- fused attention: fully cross-phase pipeline ---------------------------
__global__ __launch_bounds__(256, 2) void attn_fused_kernel(
    const bf16_t* __restrict__ qf, const bf16_t* __restrict__ kf,
    const bf16_t* __restrict__ vT,
    const unsigned char* __restrict__ mask8,
    const float* __restrict__ saw, const float* __restrict__ lse,
    float* __restrict__ out)
{
    __shared__ bf16_t vbuf[2][128 * 64];    // XOR-swizzled V tiles (16KB each)
    __shared__ bf16_t ebuf[2][64 * 72];     // exp/mask tile, merged in place (9.2KB each)
    __shared__ int mflag;

    const int tid = threadIdx.x;
    const int lane = tid & 63, w = tid >> 6;
    const int lr = lane & 15, lg = lane >> 4;

    // XCD swizzle: all 16 s-blocks of a bh share one XCD's L2
    const int di = blockIdx.y * 16 + blockIdx.x;   // 0..1023
    const int xcd = di & 7, rr = di >> 3;
    const int bh = xcd + 8 * (rr >> 4);
    const int s0 = (rr & 15) * 64;
    const int b = bh >> 4, h = bh & 15;

    if (tid == 0) {   // detect mask storage width: int32 => bytes 4i+1 all zero
        unsigned a = 0;
        for (int i = 0; i < 64; ++i) a |= mask8[4 * i + 1];
        mflag = (a == 0) ? 1 : 0;
    }
    __syncthreads();
    const bool mask_is_int = (mflag != 0);
    const int* mask32 = (const int*)mask8;

    // saw/mask staging mapping: pass j: row = (tid>>4) + 16*j, cols (tid&15)*4 .. +3
    // -> per wave-instr: 4 rows x 256B contiguous
    const int strow = tid >> 4;                    // 0..15
    const int stcol = (tid & 15) * 4;              // 0..60
    const size_t saw_base = ((size_t)bh << 20) + (size_t)(s0 + strow) * 1024 + stcol;
    const size_t m_base   = ((size_t)b << 20) + (size_t)(s0 + strow) * 1024 + stcol;

    // vT staging mapping (inverse-swizzled global source, linear LDS dest)
    const int vrow = tid >> 3;                     // 0..31 (+32 per j-round)
    const int vcol8 = (tid & 7) ^ (vrow & 7);
    const bf16_t* vt_bh = vT + (size_t)bh * 131072;

    bf16x8 aq0, aq1;
    {
        const size_t qb = ((size_t)bh * 1024 + s0 + w * 16 + lr) * 64;
        aq0 = *reinterpret_cast<const bf16x8*>(&qf[qb + lg * 8]);
        aq1 = *reinterpret_cast<const bf16x8*>(&qf[qb + 32 + lg * 8]);
    }

    const f32x4 fzero = {0.f, 0.f, 0.f, 0.f};
    f32x4 oacc[8];
#pragma unroll
    for (int i = 0; i < 8; ++i) oacc[i] = fzero;
    float rowsum[4] = {0.f, 0.f, 0.f, 0.f};

#define STAGE_VT(BUF, TILE)                                                      \
    {                                                                            \
        const bf16_t* vg = vt_bh + (size_t)(TILE) * 8192 + vcol8 * 8;            \
        char* lb = (char*)&vbuf[BUF][0] + w * 1024;                              \
        _Pragma("unroll")                                                        \
        for (int j = 0; j < 4; ++j)                                              \
            gload16(vg + (size_t)(32 * j + vrow) * 64, lb + j * 4096);           \
    }

// register-prefetch kf B-fragments for a tile (consumed one phase later)
#define LOAD_KF(TILE, KR)                                                        \
    {                                                                            \
        _Pragma("unroll")                                                        \
        for (int nt = 0; nt < 4; ++nt) {                                         \
            const size_t kb = ((size_t)bh * 1024 + (TILE) * 64 + nt * 16 + lr) * 64; \
            KR[nt * 2]     = *reinterpret_cast<const bf16x8*>(&kf[kb + lg * 8]); \
            KR[nt * 2 + 1] = *reinterpret_cast<const bf16x8*>(&kf[kb + 32 + lg * 8]); \
        }                                                                        \
    }

#define LOAD_SAWM(TILE, SS, MI, MU)                                              \
    {                                                                            \
        _Pragma("unroll")                                                        \
        for (int j = 0; j < 4; ++j)                                              \
            SS[j] = *reinterpret_cast<const float4*>(                            \
                &saw[saw_base + (size_t)(TILE) * 64 + (size_t)j * 16384]);       \
        if (mask_is_int) {                                                       \
            _Pragma("unroll")                                                    \
            for (int j = 0; j < 4; ++j)                                          \
                MI[j] = *reinterpret_cast<const int4*>(                          \
                    &mask32[m_base + (size_t)(TILE) * 64 + (size_t)j * 16384]);  \
        } else {                                                                 \
            _Pragma("unroll")                                                    \
            for (int j = 0; j < 4; ++j)                                          \
                MU[j] = *reinterpret_cast<const unsigned*>(                      \
                    &mask8[m_base + (size_t)(TILE) * 64 + (size_t)j * 16384]);   \
        }                                                                        \
    }

#define WRITE_EBUF(BUF, SS, MI, MU)                                              \
    {                                                                            \
        _Pragma("unroll")                                                        \
        for (int j = 0; j < 4; ++j) {                                            \
            int m0, m1, m2, m3;                                                  \
            if (mask_is_int) {                                                   \
                m0 = MI[j].x; m1 = MI[j].y; m2 = MI[j].z; m3 = MI[j].w;          \
            } else {                                                             \
                m0 = (int)(MU[j] & 255u);        m1 = (int)((MU[j] >> 8) & 255u);\
                m2 = (int)((MU[j] >> 16) & 255u); m3 = (int)(MU[j] >> 24);       \
            }                                                                    \
            bf16_t e[4];                                                         \
            e[0] = m0 ? (bf16_t)(-1.0f) : (bf16_t)__expf(SS[j].x);               \
            e[1] = m1 ? (bf16_t)(-1.0f) : (bf16_t)__expf(SS[j].y);               \
            e[2] = m2 ? (bf16_t)(-1.0f) : (bf16_t)__expf(SS[j].z);               \
            e[3] = m3 ? (bf16_t)(-1.0f) : (bf16_t)__expf(SS[j].w);               \
            *reinterpret_cast<uint2*>(&ebuf[BUF][(strow + 16 * j) * 72 + stcol]) \
                = *reinterpret_cast<const uint2*>(e);                            \
        }                                                                        \
    }

// one t-tile phase: QK^T (kf regs) -> in-place merge in ebuf[CUR] -> PV from vbuf[CUR]
#define PHASE(CUR, KR)                                                           \
    {                                                                            \
        f32x4 c[4];                                                              \
        _Pragma("unroll")                                                        \
        for (int nt = 0; nt < 4; ++nt) {                                         \
            f32x4 acc = fzero;                                                   \
            acc = MFMA(aq0, KR[nt * 2], acc);                                    \
            acc = MFMA(aq1, KR[nt * 2 + 1], acc);                                \
            c[nt] = acc;                                                         \
        }                                                                        \
        _Pragma("unroll")                                                        \
        for (int nt = 0; nt < 4; ++nt) {                                         \
            _Pragma("unroll")                                                    \
            for (int r = 0; r < 4; ++r) {                                        \
                const int eoff = (w * 16 + lg * 4 + r) * 72 + nt * 16 + lr;      \
                float pe = (float)ebuf[CUR][eoff];                               \
                float sc = c[nt][r];                                             \
                bool msk = pe < 0.f;                                             \
                float wv = msk ? (sc + 1e-6f) : pe;                              \
                rowsum[r] += msk ? sc : 0.f;                                     \
                ebuf[CUR][eoff] = (bf16_t)wv;                                    \
            }                                                                    \
        }                                                                        \
        asm volatile("s_waitcnt lgkmcnt(0)" ::: "memory");                       \
        __builtin_amdgcn_sched_barrier(0);                                       \
        bf16x8 ap0 = *reinterpret_cast<const bf16x8*>(                           \
            &ebuf[CUR][(w * 16 + lr) * 72 + lg * 8]);                            \
        bf16x8 ap1 = *reinterpret_cast<const bf16x8*>(                           \
            &ebuf[CUR][(w * 16 + lr) * 72 + 32 + lg * 8]);                       \
        const char* vb = (const char*)&vbuf[CUR][0];                             \
        _Pragma("unroll")                                                        \
        for (int dt = 0; dt < 8; ++dt) {                                         \
            const int row = dt * 16 + lr;                                        \
            bf16x8 v0 = *reinterpret_cast<const bf16x8*>(                        \
                vb + row * 128 + ((lg * 16) ^ xorv));                            \
            bf16x8 v1 = *reinterpret_cast<const bf16x8*>(                        \
                vb + row * 128 + ((64 + lg * 16) ^ xorv));                       \
            oacc[dt] = MFMA(ap0, v0, oacc[dt]);                                  \
            oacc[dt] = MFMA(ap1, v1, oacc[dt]);                                  \
        }                                                                        \
    }

    float4 sawA[4], sawB[4];
    int4 miA[4], miB[4];
    unsigned muA[4], muB[4];
    bf16x8 kfA[8], kfB[8];
    const int xorv = (lr & 7) << 4;

    // ---- prologue: ebuf[0]<-tile0; sawA<-tile1; kfA<-tile0; vbuf[0]<-tile0
    LOAD_SAWM(0, sawA, miA, muA);
    WRITE_EBUF(0, sawA, miA, muA);
    LOAD_SAWM(1, sawA, miA, muA);
    LOAD_KF(0, kfA);
    STAGE_VT(0, 0);
    __syncthreads();

    for (int i = 0; i < 16; i += 2) {
        // phase A: tile i (cur=0); all consumed data issued >= 1 phase ago
        STAGE_VT(1, i + 1);
        LOAD_KF(i + 1, kfB);
        LOAD_SAWM((i + 2) & 15, sawB, miB, muB);
        PHASE(0, kfA);
        WRITE_EBUF(1, sawA, miA, muA);          // tile i+1 (counted vmcnt, no drain)
        __syncthreads();
        // phase B: tile i+1 (cur=1)
        STAGE_VT(0, (i + 2) & 15);
        LOAD_KF((i + 2) & 15, kfA);
        LOAD_SAWM((i + 3) & 15, sawA, miA, muA);
        PHASE(1, kfB);
        WRITE_EBUF(0, sawB, miB, muB);          // tile i+2
        __syncthreads();
    }

    // rowsum reduce across the 16 lr lanes
#pragma unroll
    for (int r = 0; r < 4; ++r) {
        float s = rowsum[r];
#pragma unroll
        for (int m = 1; m < 16; m <<= 1) s += __shfl_xor(s, m);
        rowsum[r] = s;
    }
    float invden[4];
#pragma unroll
    for (int r = 0; r < 4; ++r) {
        const int srow = s0 + w * 16 + lg * 4 + r;
        invden[r] = 1.0f / (rowsum[r] + 1e-6f + __expf(lse[(size_t)bh * 1024 + srow]));
    }
#pragma unroll
    for (int dt = 0; dt < 8; ++dt) {
#pragma unroll
        for (int r = 0; r < 4; ++r) {
            const int srow = s0 + w * 16 + lg * 4 + r;
            out[((size_t)b * 1024 + srow) * 2048 + h * 128 + dt * 16 + lr] =
                oacc[dt][r] * invden[r];
        }
    }
#undef STAGE_VT
#undef LOAD_KF
#undef LOAD_SAWM
#undef WRITE_EBUF
#undef PHASE
}

extern "C" void kernel_launch(void* const* d_in, const int* in_sizes, int n_in,
                              void* d_out, int out_size, void* d_ws, size_t ws_size,
                              hipStream_t stream)
{
    const float* q   = (const float*)d_in[0];
    const float* k   = (const float*)d_in[1];
    const float* v   = (const float*)d_in[2];
    const unsigned char* mask = (const unsigned char*)d_in[3];
    const float* lse = (const float*)d_in[4];
    const float* saw = (const float*)d_in[5];
    const float* wq1 = (const float*)d_in[6];
    const float* wk1 = (const float*)d_in[7];
    const float* wq2 = (const float*)d_in[8];
    const float* wk2 = (const float*)d_in[9];
    const float* iK  = (const float*)d_in[10];
    const float* sD  = (const float*)d_in[11];
    const float* sD2 = (const float*)d_in[12];
    float* out = (float*)d_out;

    bf16_t* wsb  = (bf16_t*)d_ws;
    bf16_t* wq1t = wsb;                    // 16*128*128 = 262144
    bf16_t* wk1t = wq1t + 262144;
    bf16_t* wq2t = wk1t + 262144;          // 16*64*128 = 131072
    bf16_t* wk2t = wq2t + 131072;
    bf16_t* iKt  = wk2t + 131072;          // 16*64*64  = 65536
    bf16_t* qf   = iKt  + 65536;           // 4*16*1024*64 = 4194304
    bf16_t* kf   = qf   + 4194304;
    bf16_t* vT   = kf   + 4194304;         // 4*16*128*1024 = 8388608 (tiled)
    // total ws use: ~35.3 MB

    conv_weights_kernel<<<dim3(1024), dim3(256), 0, stream>>>(
        wq1, wk1, wq2, wk2, iK, wq1t, wk1t, wq2t, wk2t, iKt);
    conv_v_kernel<<<dim3(64, 16), dim3(256), 0, stream>>>(v, vT);
    feat_kernel<<<dim3(64, 16, 2), dim3(256), 0, stream>>>(
        q, k, wq1t, wq2t, wk1t, wk2t, iKt, sD, sD2, qf, kf);
    attn_fused_kernel<<<dim3(16, 64), dim3(256), 0, stream>>>(
        qf, kf, vT, mask, saw, lse, out);
}